// Round 6
// baseline (183.726 us; speedup 1.0000x reference)
//
#include <hip/hip_runtime.h>
#include <hip/hip_bf16.h>
#include <math.h>

typedef unsigned short ushort_t;
typedef unsigned int uint_t;
typedef __bf16 bf16x8 __attribute__((ext_vector_type(8)));
typedef float f32x4 __attribute__((ext_vector_type(4)));
typedef __fp16 fp16v2 __attribute__((ext_vector_type(2)));   // cvt_pkrtz result type
typedef _Float16 f16x4 __attribute__((ext_vector_type(4)));  // MFMA operand type

#define NSEQ 2048
// q pre-scale: HEAD_DIM^-0.5 * log2(e) so softmax runs in exp2 domain
#define QSCALE 0.3606737602222409f

__device__ __forceinline__ float exp2_fast(float x) {
#if __has_builtin(__builtin_amdgcn_exp2f)
    return __builtin_amdgcn_exp2f(x);
#else
    return exp2f(x);
#endif
}

union U8 { ushort_t u[8]; bf16x8 v; uint4 q; uint_t w[4]; };
union F8 { float f[8]; float4 v4[2]; };
union H4 { fp16v2 h2[2]; f16x4 v; uint_t w[2]; };
union HV { fp16v2 h2[4]; uint4 q; };

// pack two floats -> bf16x2 (v_cvt_pk_bf16_f32 on gfx950)
__device__ __forceinline__ uint_t pk2(float a, float b) {
    __hip_bfloat162 h2 = __float22bfloat162_rn(make_float2(a, b));
    union { __hip_bfloat162 h; uint_t u; } cv; cv.h = h2; return cv.u;
}

// split 8 fp32 into bf16 hi + bf16 lo (residual), packed
__device__ __forceinline__ void split8(const F8& x, U8& hi, U8& lo) {
#pragma unroll
    for (int p = 0; p < 4; ++p) {
        const float a = x.f[2*p], b = x.f[2*p+1];
        const uint_t hw = pk2(a, b);
        hi.w[p] = hw;
        const float ha = __uint_as_float(hw << 16);
        const float hb = __uint_as_float(hw & 0xFFFF0000u);
        lo.w[p] = pk2(a - ha, b - hb);
    }
}

// ---------------------------------------------------------------------------
// Kernel 0: pack Wq/Wk (B-frag order for 16x16x32, hi/lo) and Wo (same, hi/lo).
// wpk[mat][((ct*4+f)*64+lane)*8+j] = W[ct*16+(lane&15)][f*32+(lane>>4)*8+j]
// wo  [(f*64+lane)*8+j]            = Wo[lane&15][f*32+(lane>>4)*8+j]
// ---------------------------------------------------------------------------
__global__ __launch_bounds__(256) void wpack_kernel(
    const float* __restrict__ Wq, const float* __restrict__ Wk,
    const float* __restrict__ Wo,
    ushort_t* __restrict__ wpk_hi, ushort_t* __restrict__ wpk_lo,
    ushort_t* __restrict__ wo_hi, ushort_t* __restrict__ wo_lo)
{
    const int idx = blockIdx.x * 256 + threadIdx.x;   // 0..4351
    if (idx < 4096) {
        const int lane = idx & 63;
        const int f    = (idx >> 6) & 3;
        const int ct   = (idx >> 8) & 7;
        const int mat  = idx >> 11;
        const float* W = mat ? Wk : Wq;
        const float* src = W + (size_t)(ct * 16 + (lane & 15)) * 128
                             + f * 32 + (lane >> 4) * 8;
        F8 x; x.v4[0] = *(const float4*)src; x.v4[1] = *(const float4*)(src + 4);
        U8 hi, lo;
        split8(x, hi, lo);
        const size_t dst = (size_t)mat * 16384 + ((size_t)(ct * 4 + f) * 64 + lane) * 8;
        *(uint4*)(wpk_hi + dst) = hi.q;
        *(uint4*)(wpk_lo + dst) = lo.q;
    } else if (idx < 4352) {
        const int i2   = idx - 4096;     // 0..255
        const int lane = i2 & 63;
        const int f    = i2 >> 6;        // 0..3
        const float* src = Wo + (size_t)(lane & 15) * 128
                              + f * 32 + (lane >> 4) * 8;
        F8 x; x.v4[0] = *(const float4*)src; x.v4[1] = *(const float4*)(src + 4);
        U8 hi, lo;
        split8(x, hi, lo);
        const size_t dst = ((size_t)f * 64 + lane) * 8;
        *(uint4*)(wo_hi + dst) = hi.q;
        *(uint4*)(wo_lo + dst) = lo.q;
    }
}

// ---------------------------------------------------------------------------
// Kernel 1: Q/K projections on MFMA (split-bf16, XhWh+XlWh+XhWl),
// V projection + V^T store (f16) on VALU. 512 blocks x 256 threads.
// ---------------------------------------------------------------------------
__global__ __launch_bounds__(256, 2) void proj_kernel(
    const float* __restrict__ query, const float* __restrict__ key,
    const float* __restrict__ value,
    const float* __restrict__ bq, const float* __restrict__ bk,
    const float* __restrict__ Wv, const float* __restrict__ bv,
    const ushort_t* __restrict__ wpk_hi, const ushort_t* __restrict__ wpk_lo,
    ushort_t* __restrict__ q_hi, ushort_t* __restrict__ q_lo,
    ushort_t* __restrict__ k_hi, ushort_t* __restrict__ k_lo,
    ushort_t* __restrict__ vt)
{
    const int t   = threadIdx.x;
    const int w   = t >> 6;
    const int l   = t & 63;
    const int n16 = l & 15;
    const int g   = l >> 4;
    const int rbase = blockIdx.x * 16;
    const int b = rbase >> 11;

    const int isK    = w >> 1;
    const int cthalf = (w & 1) * 4;

    const float* X = isK ? key : query;
    const float* xrow = X + (size_t)(rbase + n16) * 128 + g * 8;
    bf16x8 ah[4], al[4];
#pragma unroll
    for (int f = 0; f < 4; ++f) {
        F8 x;
        x.v4[0] = *(const float4*)(xrow + f * 32);
        x.v4[1] = *(const float4*)(xrow + f * 32 + 4);
        U8 hi, lo;
        split8(x, hi, lo);
        ah[f] = hi.v; al[f] = lo.v;
    }

    const float* bias = isK ? bk : bq;
    ushort_t* dhi = isK ? k_hi : q_hi;
    ushort_t* dlo = isK ? k_lo : q_lo;
    const float scale = isK ? 1.0f : QSCALE;
    const int nbase = (rbase & 2047) + g * 4;

#pragma unroll 1
    for (int ctl = 0; ctl < 4; ++ctl) {
        const int h = cthalf + ctl;
        bf16x8 bhf[4], blf[4];
#pragma unroll
        for (int f = 0; f < 4; ++f) {
            const size_t o = (size_t)isK * 16384
                           + ((size_t)(h * 4 + f) * 64 + l) * 8;
            bhf[f] = *(const bf16x8*)(wpk_hi + o);
            blf[f] = *(const bf16x8*)(wpk_lo + o);
        }
        const float bval = bias[h * 16 + n16];
        f32x4 acc = {bval, bval, bval, bval};
#pragma unroll
        for (int f = 0; f < 4; ++f) {
            acc = __builtin_amdgcn_mfma_f32_16x16x32_bf16(ah[f], bhf[f], acc, 0, 0, 0);
            acc = __builtin_amdgcn_mfma_f32_16x16x32_bf16(al[f], bhf[f], acc, 0, 0, 0);
            acc = __builtin_amdgcn_mfma_f32_16x16x32_bf16(ah[f], blf[f], acc, 0, 0, 0);
        }
        const size_t abase = ((size_t)(b * 8 + h) * NSEQ + nbase) * 16 + n16;
        const float a0 = acc[0]*scale, a1 = acc[1]*scale;
        const float a2 = acc[2]*scale, a3 = acc[3]*scale;
        const uint_t h01 = pk2(a0, a1), h23 = pk2(a2, a3);
        const uint_t l01 = pk2(a0 - __uint_as_float(h01 << 16),
                               a1 - __uint_as_float(h01 & 0xFFFF0000u));
        const uint_t l23 = pk2(a2 - __uint_as_float(h23 << 16),
                               a3 - __uint_as_float(h23 & 0xFFFF0000u));
        dhi[abase]      = (ushort_t)h01;
        dhi[abase + 16] = (ushort_t)(h01 >> 16);
        dhi[abase + 32] = (ushort_t)h23;
        dhi[abase + 48] = (ushort_t)(h23 >> 16);
        dlo[abase]      = (ushort_t)l01;
        dlo[abase + 16] = (ushort_t)(l01 >> 16);
        dlo[abase + 32] = (ushort_t)l23;
        dlo[abase + 48] = (ushort_t)(l23 >> 16);
    }

    // V projection (VALU, K=16) + vt transpose store in f16
    const int e  = t & 127;
    const int rh = t >> 7;
    const int r0 = rbase + rh * 8;
    const float4* Wv4 = (const float4*)(Wv + (size_t)e * 16);
    const float4 wv0 = Wv4[0], wv1 = Wv4[1], wv2 = Wv4[2], wv3 = Wv4[3];
    const float bvv = bv[e];
    F8 af;
#pragma unroll
    for (int r = 0; r < 8; ++r) {
        const float4* xv4 = (const float4*)(value + (size_t)(r0 + r) * 16);
        const float4 x0 = xv4[0], x1 = xv4[1], x2 = xv4[2], x3 = xv4[3];
        float a = bvv;
        a += wv0.x*x0.x + wv0.y*x0.y + wv0.z*x0.z + wv0.w*x0.w;
        a += wv1.x*x1.x + wv1.y*x1.y + wv1.z*x1.z + wv1.w*x1.w;
        a += wv2.x*x2.x + wv2.y*x2.y + wv2.z*x2.z + wv2.w*x2.w;
        a += wv3.x*x3.x + wv3.y*x3.y + wv3.z*x3.z + wv3.w*x3.w;
        af.f[r] = a;
    }
    HV vpk;
#pragma unroll
    for (int p = 0; p < 4; ++p)
        vpk.h2[p] = __builtin_amdgcn_cvt_pkrtz(af.f[2*p], af.f[2*p+1]);
    const int hv = e >> 4, dd = e & 15;
    *(uint4*)(vt + ((size_t)(b * 8 + hv) * 16 + dd) * NSEQ + (r0 & 2047)) = vpk.q;
}

// ---------------------------------------------------------------------------
// Kernel 2: fused two-phase flash attention, split-K x2, no LDS in hot loop.
// Block: 4 waves; wave w: qsub=w&1 (16 q rows), kh=w>>1 (1024-key half).
// Phase 1: row max over own half (hi-score MFMA), LDS max-exchange w <-> w^2.
// Phase 2: exact scores (3-product split-bf16), exp2, p -> f16 B-frag
//          IN REGISTER (C-layout of 16x16 == B-layout of 16x16x16), PV and
//          l via v_mfma_f32_16x16x16f16. Combine halves via LDS at the end.
// Output: ctx bf16, row-major [B][N][128].
// ---------------------------------------------------------------------------
__global__ __launch_bounds__(256, 6) void attn_kernel(
    const ushort_t* __restrict__ q_hi, const ushort_t* __restrict__ q_lo,
    const ushort_t* __restrict__ k_hi, const ushort_t* __restrict__ k_lo,
    const ushort_t* __restrict__ vt, ushort_t* __restrict__ ctxb)
{
    const int t    = threadIdx.x;
    const int w    = t >> 6;
    const int l    = t & 63;
    const int col  = l & 15;
    const int g    = l >> 4;
    const int qsub = w & 1;
    const int kh   = w >> 1;

    const int bh = blockIdx.y;
    const int qb = blockIdx.x * 32 + qsub * 16;

    __shared__ float lds_m[64];
    __shared__ __align__(16) float lds_o[4][16][16];
    __shared__ float lds_l[4][16];

    U8 Uz;
#pragma unroll
    for (int i = 0; i < 8; ++i) Uz.u[i] = 0;
    const bf16x8 zf = Uz.v;

    // Q B-fragments (16x16x32): b1=[qhi|qhi], b2=[qlo|0]
    const size_t qoff = ((size_t)(bh * NSEQ + qb + col)) * 16 + (g & 1) * 8;
    const bf16x8 bq1 = *(const bf16x8*)(q_hi + qoff);
    bf16x8 bq2 = *(const bf16x8*)(q_lo + qoff);
    bq2 = (g < 2) ? bq2 : zf;

    // K A-fragment base (g0,1: k_hi dims; g2,3: k_lo dims -> folded product)
    const ushort_t* ksel = (g < 2) ? k_hi : k_lo;
    const ushort_t* aptr = ksel + ((size_t)bh * NSEQ + col) * 16 + (g & 1) * 8
                         + (size_t)kh * 1024 * 16;
    // V^T f16 base: row vd=col, this wave's key half
    const ushort_t* vp = vt + ((size_t)bh * 16 + col) * NSEQ + kh * 1024;

    // ---- Phase 1: max over this wave's 1024 keys ----
    float mrun = -INFINITY;
    const f32x4 z = {0.f, 0.f, 0.f, 0.f};
#pragma unroll 2
    for (int kb = 0; kb < 32; ++kb) {
        const bf16x8 a1 = *(const bf16x8*)(aptr + (size_t)kb * 512);
        const bf16x8 a2 = *(const bf16x8*)(aptr + (size_t)kb * 512 + 256);
        const f32x4 s1 = __builtin_amdgcn_mfma_f32_16x16x32_bf16(a1, bq1, z, 0, 0, 0);
        const f32x4 s2 = __builtin_amdgcn_mfma_f32_16x16x32_bf16(a2, bq1, z, 0, 0, 0);
        mrun = fmaxf(mrun, fmaxf(fmaxf(s1[0], s1[1]), fmaxf(s1[2], s1[3])));
        mrun = fmaxf(mrun, fmaxf(fmaxf(s2[0], s2[1]), fmaxf(s2[2], s2[3])));
    }
    mrun = fmaxf(mrun, __shfl_xor(mrun, 16));
    mrun = fmaxf(mrun, __shfl_xor(mrun, 32));
    if (l < 16) lds_m[w * 16 + col] = mrun;
    __syncthreads();
    const float mfin = fmaxf(mrun, lds_m[(w ^ 2) * 16 + col]);
    const f32x4 zin = {-mfin, -mfin, -mfin, -mfin};

    // ---- Phase 2: exp-sum + PV over the same (cache-warm) half ----
    f32x4 o    = {0.f, 0.f, 0.f, 0.f};
    f32x4 lacc = {0.f, 0.f, 0.f, 0.f};
    const f16x4 onesh = {(_Float16)1.f, (_Float16)1.f, (_Float16)1.f, (_Float16)1.f};

    bf16x8 a1 = *(const bf16x8*)(aptr);
    bf16x8 a2 = *(const bf16x8*)(aptr + 256);
    f16x4 av1 = *(const f16x4*)(vp + g * 4);
    f16x4 av2 = *(const f16x4*)(vp + 16 + g * 4);

    for (int kb = 0; kb < 32; ++kb) {
        const int kn = (kb + 1) & 31;            // wrap: harmless dummy on last
        bf16x8 na1 = *(const bf16x8*)(aptr + (size_t)kn * 512);
        bf16x8 na2 = *(const bf16x8*)(aptr + (size_t)kn * 512 + 256);
        f16x4 nav1 = *(const f16x4*)(vp + kn * 32 + g * 4);
        f16x4 nav2 = *(const f16x4*)(vp + kn * 32 + 16 + g * 4);

        // S^T - m  (C init carries -m); keys 4g+r per lane, col=q
        f32x4 st1 = __builtin_amdgcn_mfma_f32_16x16x32_bf16(a1, bq2, zin, 0, 0, 0);
        st1       = __builtin_amdgcn_mfma_f32_16x16x32_bf16(a1, bq1, st1, 0, 0, 0);
        f32x4 st2 = __builtin_amdgcn_mfma_f32_16x16x32_bf16(a2, bq2, zin, 0, 0, 0);
        st2       = __builtin_amdgcn_mfma_f32_16x16x32_bf16(a2, bq1, st2, 0, 0, 0);

        // p in f16: C-layout == B-layout of 16x16x16 -> no transpose needed
        H4 b1u, b2u;
        b1u.h2[0] = __builtin_amdgcn_cvt_pkrtz(exp2_fast(st1[0]), exp2_fast(st1[1]));
        b1u.h2[1] = __builtin_amdgcn_cvt_pkrtz(exp2_fast(st1[2]), exp2_fast(st1[3]));
        b2u.h2[0] = __builtin_amdgcn_cvt_pkrtz(exp2_fast(st2[0]), exp2_fast(st2[1]));
        b2u.h2[1] = __builtin_amdgcn_cvt_pkrtz(exp2_fast(st2[2]), exp2_fast(st2[3]));

        o    = __builtin_amdgcn_mfma_f32_16x16x16f16(av1,   b1u.v, o,    0, 0, 0);
        lacc = __builtin_amdgcn_mfma_f32_16x16x16f16(onesh, b1u.v, lacc, 0, 0, 0);
        o    = __builtin_amdgcn_mfma_f32_16x16x16f16(av2,   b2u.v, o,    0, 0, 0);
        lacc = __builtin_amdgcn_mfma_f32_16x16x16f16(onesh, b2u.v, lacc, 0, 0, 0);

        a1 = na1; a2 = na2; av1 = nav1; av2 = nav2;
    }

    // ---- Combine the two key-halves (exact: same m) ----
    *(f32x4*)&lds_o[w][col][4 * g] = o;
    if (l < 16) lds_l[w][col] = lacc[0];
    __syncthreads();
    if (w < 2) {
        const f32x4 oA = *(const f32x4*)&lds_o[w][col][4 * g];
        const f32x4 oB = *(const f32x4*)&lds_o[w + 2][col][4 * g];
        const float li = 1.0f / (lds_l[w][col] + lds_l[w + 2][col]);
        const float r0 = (oA[0] + oB[0]) * li;
        const float r1 = (oA[1] + oB[1]) * li;
        const float r2 = (oA[2] + oB[2]) * li;
        const float r3 = (oA[3] + oB[3]) * li;
        const int b = bh >> 3, h = bh & 7;
        uint2 pkd; pkd.x = pk2(r0, r1); pkd.y = pk2(r2, r3);
        *(uint2*)(ctxb + ((size_t)(b * NSEQ + qb + col)) * 128 + h * 16 + 4 * g) = pkd;
    }
}

// ---------------------------------------------------------------------------
// Kernel 3: output projection on MFMA (split-bf16 Wo). ctx bf16 row-major.
// grid 128 x 256 thr: wave w -> 16 rows. out[m=row][n=j].
// ---------------------------------------------------------------------------
__global__ __launch_bounds__(256) void outproj_kernel(
    const ushort_t* __restrict__ ctxb,
    const ushort_t* __restrict__ wo_hi, const ushort_t* __restrict__ wo_lo,
    const float* __restrict__ bo, float* __restrict__ out)
{
    const int t   = threadIdx.x;
    const int w   = t >> 6;
    const int l   = t & 63;
    const int col = l & 15;
    const int g   = l >> 4;
    const int row0 = blockIdx.x * 64 + w * 16;

    const float bval = bo[col];
    f32x4 acc = {bval, bval, bval, bval};
    const ushort_t* ar = ctxb + (size_t)(row0 + col) * 128 + g * 8;
#pragma unroll
    for (int f = 0; f < 4; ++f) {
        const bf16x8 a = *(const bf16x8*)(ar + f * 32);
        const size_t o = ((size_t)f * 64 + l) * 8;
        const bf16x8 bh_ = *(const bf16x8*)(wo_hi + o);
        const bf16x8 bl_ = *(const bf16x8*)(wo_lo + o);
        acc = __builtin_amdgcn_mfma_f32_16x16x32_bf16(a, bh_, acc, 0, 0, 0);
        acc = __builtin_amdgcn_mfma_f32_16x16x32_bf16(a, bl_, acc, 0, 0, 0);
    }
#pragma unroll
    for (int r = 0; r < 4; ++r)
        out[(size_t)(row0 + 4 * g + r) * 16 + col] = acc[r];
}

// ---------------------------------------------------------------------------
extern "C" void kernel_launch(void* const* d_in, const int* in_sizes, int n_in,
                              void* d_out, int out_size, void* d_ws, size_t ws_size,
                              hipStream_t stream)
{
    const float* query = (const float*)d_in[0];
    const float* key_  = (const float*)d_in[1];
    const float* value = (const float*)d_in[2];
    const float* Wq = (const float*)d_in[3];
    const float* bq = (const float*)d_in[4];
    const float* Wk = (const float*)d_in[5];
    const float* bk = (const float*)d_in[6];
    const float* Wv = (const float*)d_in[7];
    const float* bv = (const float*)d_in[8];
    const float* Wo = (const float*)d_in[9];
    const float* bo = (const float*)d_in[10];
    float* out = (float*)d_out;

    ushort_t* base = (ushort_t*)d_ws;
    ushort_t* q_hi = base;
    ushort_t* q_lo = base + (1u << 20);
    ushort_t* k_hi = base + (2u << 20);
    ushort_t* k_lo = base + (3u << 20);
    ushort_t* vt   = base + (4u << 20);
    ushort_t* ctxb = base + (5u << 20);
    ushort_t* wpk_hi = base + (6u << 20);
    ushort_t* wpk_lo = wpk_hi + 32768;
    ushort_t* wo_hi  = wpk_hi + 65536;
    ushort_t* wo_lo  = wo_hi + 2048;

    wpack_kernel<<<dim3(17), dim3(256), 0, stream>>>(
        Wq, Wk, Wo, wpk_hi, wpk_lo, wo_hi, wo_lo);
    proj_kernel<<<dim3(512), dim3(256), 0, stream>>>(
        query, key_, value, bq, bk, Wv, bv, wpk_hi, wpk_lo,
        q_hi, q_lo, k_hi, k_lo, vt);
    attn_kernel<<<dim3(64, 32), dim3(256), 0, stream>>>(
        q_hi, q_lo, k_hi, k_lo, vt, ctxb);
    outproj_kernel<<<dim3(128), dim3(256), 0, stream>>>(
        ctxb, wo_hi, wo_lo, bo, out);
}

// Round 7
// 135.352 us; speedup vs baseline: 1.3574x; 1.3574x over previous
//
#include <hip/hip_runtime.h>
#include <hip/hip_bf16.h>
#include <math.h>

typedef unsigned short ushort_t;
typedef unsigned int uint_t;
typedef __bf16 bf16x8 __attribute__((ext_vector_type(8)));
typedef float f32x4 __attribute__((ext_vector_type(4)));
typedef __fp16 fp16v2 __attribute__((ext_vector_type(2)));   // cvt_pkrtz result type
typedef _Float16 f16x4 __attribute__((ext_vector_type(4)));  // MFMA operand type

#define NSEQ 2048
// q pre-scale: HEAD_DIM^-0.5 * log2(e) so softmax runs in exp2 domain
#define QSCALE 0.3606737602222409f

__device__ __forceinline__ float exp2_fast(float x) {
#if __has_builtin(__builtin_amdgcn_exp2f)
    return __builtin_amdgcn_exp2f(x);
#else
    return exp2f(x);
#endif
}

union U8 { ushort_t u[8]; bf16x8 v; uint4 q; uint_t w[4]; };
union F8 { float f[8]; float4 v4[2]; };
union H4 { fp16v2 h2[2]; f16x4 v; uint_t w[2]; };
union HV { fp16v2 h2[4]; uint4 q; };

// pack two floats -> bf16x2 (v_cvt_pk_bf16_f32 on gfx950)
__device__ __forceinline__ uint_t pk2(float a, float b) {
    __hip_bfloat162 h2 = __float22bfloat162_rn(make_float2(a, b));
    union { __hip_bfloat162 h; uint_t u; } cv; cv.h = h2; return cv.u;
}

// split 8 fp32 into bf16 hi + bf16 lo (residual), packed
__device__ __forceinline__ void split8(const F8& x, U8& hi, U8& lo) {
#pragma unroll
    for (int p = 0; p < 4; ++p) {
        const float a = x.f[2*p], b = x.f[2*p+1];
        const uint_t hw = pk2(a, b);
        hi.w[p] = hw;
        const float ha = __uint_as_float(hw << 16);
        const float hb = __uint_as_float(hw & 0xFFFF0000u);
        lo.w[p] = pk2(a - ha, b - hb);
    }
}

// ---------------------------------------------------------------------------
// Kernel 0: pack Wq/Wk (A-frag order for 16x16x32, hi/lo) and Wo (B-frag).
// wpk[mat][((ct*4+f)*64+lane)*8+j] = W[ct*16+(lane&15)][f*32+(lane>>4)*8+j]
// (A and B fragment index math is identical: m/n = lane&15, k = (lane>>4)*8+j)
// ---------------------------------------------------------------------------
__global__ __launch_bounds__(256) void wpack_kernel(
    const float* __restrict__ Wq, const float* __restrict__ Wk,
    const float* __restrict__ Wo,
    ushort_t* __restrict__ wpk_hi, ushort_t* __restrict__ wpk_lo,
    ushort_t* __restrict__ wo_hi, ushort_t* __restrict__ wo_lo)
{
    const int idx = blockIdx.x * 256 + threadIdx.x;   // 0..4351
    if (idx < 4096) {
        const int lane = idx & 63;
        const int f    = (idx >> 6) & 3;
        const int ct   = (idx >> 8) & 7;
        const int mat  = idx >> 11;
        const float* W = mat ? Wk : Wq;
        const float* src = W + (size_t)(ct * 16 + (lane & 15)) * 128
                             + f * 32 + (lane >> 4) * 8;
        F8 x; x.v4[0] = *(const float4*)src; x.v4[1] = *(const float4*)(src + 4);
        U8 hi, lo;
        split8(x, hi, lo);
        const size_t dst = (size_t)mat * 16384 + ((size_t)(ct * 4 + f) * 64 + lane) * 8;
        *(uint4*)(wpk_hi + dst) = hi.q;
        *(uint4*)(wpk_lo + dst) = lo.q;
    } else if (idx < 4352) {
        const int i2   = idx - 4096;     // 0..255
        const int lane = i2 & 63;
        const int f    = i2 >> 6;        // 0..3
        const float* src = Wo + (size_t)(lane & 15) * 128
                              + f * 32 + (lane >> 4) * 8;
        F8 x; x.v4[0] = *(const float4*)src; x.v4[1] = *(const float4*)(src + 4);
        U8 hi, lo;
        split8(x, hi, lo);
        const size_t dst = ((size_t)f * 64 + lane) * 8;
        *(uint4*)(wo_hi + dst) = hi.q;
        *(uint4*)(wo_lo + dst) = lo.q;
    }
}

// ---------------------------------------------------------------------------
// Kernel 1: Q/K projections on MFMA, operands SWAPPED vs R6: A = W (m=outdim),
// B = X (n=token) -> C cols = tokens, rows = dims -> epilogue is two 8B
// coalesced stores per head-tile (wave covers a full contiguous 512B block).
// Head-tile loop fully unrolled: all W-fragment loads issue in one batch.
// V projection + V^T store (f16) on VALU. 512 blocks x 256 threads.
// ---------------------------------------------------------------------------
__global__ __launch_bounds__(256, 2) void proj_kernel(
    const float* __restrict__ query, const float* __restrict__ key,
    const float* __restrict__ value,
    const float* __restrict__ bq, const float* __restrict__ bk,
    const float* __restrict__ Wv, const float* __restrict__ bv,
    const ushort_t* __restrict__ wpk_hi, const ushort_t* __restrict__ wpk_lo,
    ushort_t* __restrict__ q_hi, ushort_t* __restrict__ q_lo,
    ushort_t* __restrict__ k_hi, ushort_t* __restrict__ k_lo,
    ushort_t* __restrict__ vt)
{
    const int t   = threadIdx.x;
    const int w   = t >> 6;
    const int l   = t & 63;
    const int col = l & 15;          // token within block (B col / C col)
    const int g   = l >> 4;
    const int rbase = blockIdx.x * 16;
    const int b = rbase >> 11;

    const int isK    = w >> 1;
    const int cthalf = (w & 1) * 4;

    // B fragments from X: token rbase+col, k = f*32 + g*8 + j, fp32 -> hi/lo
    const float* X = isK ? key : query;
    const float* xrow = X + (size_t)(rbase + col) * 128 + g * 8;
    bf16x8 xh[4], xl[4];
#pragma unroll
    for (int f = 0; f < 4; ++f) {
        F8 x;
        x.v4[0] = *(const float4*)(xrow + f * 32);
        x.v4[1] = *(const float4*)(xrow + f * 32 + 4);
        U8 hi, lo;
        split8(x, hi, lo);
        xh[f] = hi.v; xl[f] = lo.v;
    }

    const float* bias = isK ? bk : bq;
    ushort_t* dhi = isK ? k_hi : q_hi;
    ushort_t* dlo = isK ? k_lo : q_lo;
    const float scale = isK ? 1.0f : QSCALE;
    const int tok = (rbase & 2047) + col;

#pragma unroll
    for (int ctl = 0; ctl < 4; ++ctl) {
        const int h = cthalf + ctl;
        bf16x8 whf[4], wlf[4];
#pragma unroll
        for (int f = 0; f < 4; ++f) {
            const size_t o = (size_t)isK * 16384
                           + ((size_t)(h * 4 + f) * 64 + l) * 8;
            whf[f] = *(const bf16x8*)(wpk_hi + o);
            wlf[f] = *(const bf16x8*)(wpk_lo + o);
        }
        const float4 b4 = *(const float4*)(bias + h * 16 + 4 * g);
        f32x4 acc = {b4.x, b4.y, b4.z, b4.w};
#pragma unroll
        for (int f = 0; f < 4; ++f) {
            acc = __builtin_amdgcn_mfma_f32_16x16x32_bf16(whf[f], xh[f], acc, 0, 0, 0);
            acc = __builtin_amdgcn_mfma_f32_16x16x32_bf16(wlf[f], xh[f], acc, 0, 0, 0);
            acc = __builtin_amdgcn_mfma_f32_16x16x32_bf16(whf[f], xl[f], acc, 0, 0, 0);
        }
        // rows = dims 4g..4g+3 of token col -> contiguous 8B hi + 8B lo
        const size_t abase = ((size_t)(b * 8 + h) * NSEQ + tok) * 16 + 4 * g;
        const float a0 = acc[0]*scale, a1 = acc[1]*scale;
        const float a2 = acc[2]*scale, a3 = acc[3]*scale;
        const uint_t h01 = pk2(a0, a1), h23 = pk2(a2, a3);
        const uint_t l01 = pk2(a0 - __uint_as_float(h01 << 16),
                               a1 - __uint_as_float(h01 & 0xFFFF0000u));
        const uint_t l23 = pk2(a2 - __uint_as_float(h23 << 16),
                               a3 - __uint_as_float(h23 & 0xFFFF0000u));
        uint2 sh; sh.x = h01; sh.y = h23;
        uint2 sl; sl.x = l01; sl.y = l23;
        *(uint2*)(dhi + abase) = sh;
        *(uint2*)(dlo + abase) = sl;
    }

    // V projection (VALU, K=16) + vt transpose store in f16
    const int e  = t & 127;
    const int rh = t >> 7;
    const int r0 = rbase + rh * 8;
    const float4* Wv4 = (const float4*)(Wv + (size_t)e * 16);
    const float4 wv0 = Wv4[0], wv1 = Wv4[1], wv2 = Wv4[2], wv3 = Wv4[3];
    const float bvv = bv[e];
    F8 af;
#pragma unroll
    for (int r = 0; r < 8; ++r) {
        const float4* xv4 = (const float4*)(value + (size_t)(r0 + r) * 16);
        const float4 x0 = xv4[0], x1 = xv4[1], x2 = xv4[2], x3 = xv4[3];
        float a = bvv;
        a += wv0.x*x0.x + wv0.y*x0.y + wv0.z*x0.z + wv0.w*x0.w;
        a += wv1.x*x1.x + wv1.y*x1.y + wv1.z*x1.z + wv1.w*x1.w;
        a += wv2.x*x2.x + wv2.y*x2.y + wv2.z*x2.z + wv2.w*x2.w;
        a += wv3.x*x3.x + wv3.y*x3.y + wv3.z*x3.z + wv3.w*x3.w;
        af.f[r] = a;
    }
    HV vpk;
#pragma unroll
    for (int p = 0; p < 4; ++p)
        vpk.h2[p] = __builtin_amdgcn_cvt_pkrtz(af.f[2*p], af.f[2*p+1]);
    const int hv = e >> 4, dd = e & 15;
    *(uint4*)(vt + ((size_t)(b * 8 + hv) * 16 + dd) * NSEQ + (r0 & 2047)) = vpk.q;
}

// ---------------------------------------------------------------------------
// Kernel 2: fused two-phase flash attention. XCD-local block swizzle: all 32
// blocks of a bh land on one XCD (L2-resident K/V). Each wave: 32 q rows
// (2 subtiles sharing K/V loads -> 2x arithmetic intensity, 2 indep o-chains)
// x 1024 keys. 2-deep prefetch. l-sum on VALU (no ones-MFMA).
// grid 1024 x 256 thr, launch_bounds(256,4): 4 blocks/CU.
// ---------------------------------------------------------------------------
__global__ __launch_bounds__(256, 4) void attn_kernel(
    const ushort_t* __restrict__ q_hi, const ushort_t* __restrict__ q_lo,
    const ushort_t* __restrict__ k_hi, const ushort_t* __restrict__ k_lo,
    const ushort_t* __restrict__ vt, ushort_t* __restrict__ ctxb)
{
    const int t    = threadIdx.x;
    const int w    = t >> 6;
    const int l    = t & 63;
    const int col  = l & 15;
    const int g    = l >> 4;
    const int qsub = w & 1;
    const int kh   = w >> 1;

    // XCD-aware decode: bh's 32 q-blocks all have id % 8 == bh % 8
    const int id   = blockIdx.x;
    const int rest = id >> 3;
    const int bh   = (rest >> 5) * 8 + (id & 7);
    const int qbase = (rest & 31) * 64 + qsub * 32;

    __shared__ float lds_m[4][32];
    __shared__ __align__(16) float lds_o[2][2][16][16];
    __shared__ float lds_l[2][2][16];

    U8 Uz;
#pragma unroll
    for (int i = 0; i < 8; ++i) Uz.u[i] = 0;
    const bf16x8 zf = Uz.v;

    // Q fragments for 2 subtiles: b1=[qhi|qhi], b2=[qlo|0]
    bf16x8 bq1[2], bq2[2];
#pragma unroll
    for (int s = 0; s < 2; ++s) {
        const size_t qoff = ((size_t)(bh * NSEQ + qbase + s * 16 + col)) * 16 + (g & 1) * 8;
        bq1[s] = *(const bf16x8*)(q_hi + qoff);
        const bf16x8 t2 = *(const bf16x8*)(q_lo + qoff);
        bq2[s] = (g < 2) ? t2 : zf;
    }

    const ushort_t* ksel = (g < 2) ? k_hi : k_lo;
    const ushort_t* aptr = ksel + ((size_t)bh * NSEQ + col) * 16 + (g & 1) * 8
                         + (size_t)kh * (1024 * 16);
    const ushort_t* vp = vt + ((size_t)bh * 16 + col) * NSEQ + kh * 1024;

    // ---- Phase 1: max over this wave's 1024 keys, both subtiles ----
    float m0 = -INFINITY, m1 = -INFINITY;
    const f32x4 z = {0.f, 0.f, 0.f, 0.f};
    bf16x8 pa1[2], pa2[2];
    pa1[0] = *(const bf16x8*)(aptr);
    pa2[0] = *(const bf16x8*)(aptr + 256);
    pa1[1] = *(const bf16x8*)(aptr + 512);
    pa2[1] = *(const bf16x8*)(aptr + 768);
#pragma unroll 2
    for (int kb = 0; kb < 32; ++kb) {
        const bf16x8 c1 = pa1[kb & 1], c2 = pa2[kb & 1];
        const int kn = (kb + 2) & 31;          // wrap: reloads kb 0,1 at the end
        pa1[kb & 1] = *(const bf16x8*)(aptr + (size_t)kn * 512);
        pa2[kb & 1] = *(const bf16x8*)(aptr + (size_t)kn * 512 + 256);
        const f32x4 s1 = __builtin_amdgcn_mfma_f32_16x16x32_bf16(c1, bq1[0], z, 0, 0, 0);
        const f32x4 s2 = __builtin_amdgcn_mfma_f32_16x16x32_bf16(c2, bq1[0], z, 0, 0, 0);
        const f32x4 s3 = __builtin_amdgcn_mfma_f32_16x16x32_bf16(c1, bq1[1], z, 0, 0, 0);
        const f32x4 s4 = __builtin_amdgcn_mfma_f32_16x16x32_bf16(c2, bq1[1], z, 0, 0, 0);
        m0 = fmaxf(m0, fmaxf(fmaxf(s1[0], s1[1]), fmaxf(s1[2], s1[3])));
        m0 = fmaxf(m0, fmaxf(fmaxf(s2[0], s2[1]), fmaxf(s2[2], s2[3])));
        m1 = fmaxf(m1, fmaxf(fmaxf(s3[0], s3[1]), fmaxf(s3[2], s3[3])));
        m1 = fmaxf(m1, fmaxf(fmaxf(s4[0], s4[1]), fmaxf(s4[2], s4[3])));
    }
    m0 = fmaxf(m0, __shfl_xor(m0, 16)); m0 = fmaxf(m0, __shfl_xor(m0, 32));
    m1 = fmaxf(m1, __shfl_xor(m1, 16)); m1 = fmaxf(m1, __shfl_xor(m1, 32));
    if (l < 32) lds_m[w][l] = (l < 16) ? m0 : m1;
    __syncthreads();
    const float mf0 = fmaxf(m0, lds_m[w ^ 2][col]);
    const float mf1 = fmaxf(m1, lds_m[w ^ 2][col + 16]);
    const f32x4 zin0 = {-mf0, -mf0, -mf0, -mf0};
    const f32x4 zin1 = {-mf1, -mf1, -mf1, -mf1};

    // ---- Phase 2: exp-sum + PV (pa slots already hold kb=0,1) ----
    f32x4 o0 = {0.f,0.f,0.f,0.f}, o1 = {0.f,0.f,0.f,0.f};
    float ls0 = 0.f, ls1 = 0.f;
    f16x4 pv1[2], pv2[2];
    pv1[0] = *(const f16x4*)(vp + g * 4);
    pv2[0] = *(const f16x4*)(vp + 16 + g * 4);
    pv1[1] = *(const f16x4*)(vp + 32 + g * 4);
    pv2[1] = *(const f16x4*)(vp + 48 + g * 4);

#pragma unroll 2
    for (int kb = 0; kb < 32; ++kb) {
        const bf16x8 c1 = pa1[kb & 1], c2 = pa2[kb & 1];
        const f16x4 v1 = pv1[kb & 1], v2 = pv2[kb & 1];
        const int kn = (kb + 2) & 31;
        pa1[kb & 1] = *(const bf16x8*)(aptr + (size_t)kn * 512);
        pa2[kb & 1] = *(const bf16x8*)(aptr + (size_t)kn * 512 + 256);
        pv1[kb & 1] = *(const f16x4*)(vp + kn * 32 + g * 4);
        pv2[kb & 1] = *(const f16x4*)(vp + kn * 32 + 16 + g * 4);

        // subtile 0
        {
            f32x4 st1 = __builtin_amdgcn_mfma_f32_16x16x32_bf16(c1, bq2[0], zin0, 0, 0, 0);
            st1       = __builtin_amdgcn_mfma_f32_16x16x32_bf16(c1, bq1[0], st1, 0, 0, 0);
            f32x4 st2 = __builtin_amdgcn_mfma_f32_16x16x32_bf16(c2, bq2[0], zin0, 0, 0, 0);
            st2       = __builtin_amdgcn_mfma_f32_16x16x32_bf16(c2, bq1[0], st2, 0, 0, 0);
            const float p0 = exp2_fast(st1[0]), p1 = exp2_fast(st1[1]);
            const float p2 = exp2_fast(st1[2]), p3 = exp2_fast(st1[3]);
            const float p4 = exp2_fast(st2[0]), p5 = exp2_fast(st2[1]);
            const float p6 = exp2_fast(st2[2]), p7 = exp2_fast(st2[3]);
            ls0 += ((p0 + p1) + (p2 + p3)) + ((p4 + p5) + (p6 + p7));
            H4 b1u, b2u;
            b1u.h2[0] = __builtin_amdgcn_cvt_pkrtz(p0, p1);
            b1u.h2[1] = __builtin_amdgcn_cvt_pkrtz(p2, p3);
            b2u.h2[0] = __builtin_amdgcn_cvt_pkrtz(p4, p5);
            b2u.h2[1] = __builtin_amdgcn_cvt_pkrtz(p6, p7);
            o0 = __builtin_amdgcn_mfma_f32_16x16x16f16(v1, b1u.v, o0, 0, 0, 0);
            o0 = __builtin_amdgcn_mfma_f32_16x16x16f16(v2, b2u.v, o0, 0, 0, 0);
        }
        // subtile 1
        {
            f32x4 st1 = __builtin_amdgcn_mfma_f32_16x16x32_bf16(c1, bq2[1], zin1, 0, 0, 0);
            st1       = __builtin_amdgcn_mfma_f32_16x16x32_bf16(c1, bq1[1], st1, 0, 0, 0);
            f32x4 st2 = __builtin_amdgcn_mfma_f32_16x16x32_bf16(c2, bq2[1], zin1, 0, 0, 0);
            st2       = __builtin_amdgcn_mfma_f32_16x16x32_bf16(c2, bq1[1], st2, 0, 0, 0);
            const float p0 = exp2_fast(st1[0]), p1 = exp2_fast(st1[1]);
            const float p2 = exp2_fast(st1[2]), p3 = exp2_fast(st1[3]);
            const float p4 = exp2_fast(st2[0]), p5 = exp2_fast(st2[1]);
            const float p6 = exp2_fast(st2[2]), p7 = exp2_fast(st2[3]);
            ls1 += ((p0 + p1) + (p2 + p3)) + ((p4 + p5) + (p6 + p7));
            H4 b1u, b2u;
            b1u.h2[0] = __builtin_amdgcn_cvt_pkrtz(p0, p1);
            b1u.h2[1] = __builtin_amdgcn_cvt_pkrtz(p2, p3);
            b2u.h2[0] = __builtin_amdgcn_cvt_pkrtz(p4, p5);
            b2u.h2[1] = __builtin_amdgcn_cvt_pkrtz(p6, p7);
            o1 = __builtin_amdgcn_mfma_f32_16x16x16f16(v1, b1u.v, o1, 0, 0, 0);
            o1 = __builtin_amdgcn_mfma_f32_16x16x16f16(v2, b2u.v, o1, 0, 0, 0);
        }
    }

    ls0 += __shfl_xor(ls0, 16); ls0 += __shfl_xor(ls0, 32);
    ls1 += __shfl_xor(ls1, 16); ls1 += __shfl_xor(ls1, 32);

    // ---- Combine the two key-halves (exact: same m) ----
    if (w >= 2) {
        *(f32x4*)&lds_o[w - 2][0][col][4 * g] = o0;
        *(f32x4*)&lds_o[w - 2][1][col][4 * g] = o1;
        if (l < 32) lds_l[w - 2][l >> 4][col] = (l < 16) ? ls0 : ls1;
    }
    __syncthreads();
    if (w < 2) {
        const int b = bh >> 3, h = bh & 7;
#pragma unroll
        for (int s = 0; s < 2; ++s) {
            const f32x4 ob = *(const f32x4*)&lds_o[w][s][col][4 * g];
            const f32x4 oa = s ? o1 : o0;
            const float lt = (s ? ls1 : ls0) + lds_l[w][s][col];
            const float li = 1.0f / lt;
            const float r0 = (oa[0] + ob[0]) * li;
            const float r1 = (oa[1] + ob[1]) * li;
            const float r2 = (oa[2] + ob[2]) * li;
            const float r3 = (oa[3] + ob[3]) * li;
            uint2 pkd; pkd.x = pk2(r0, r1); pkd.y = pk2(r2, r3);
            *(uint2*)(ctxb + ((size_t)(b * NSEQ + qbase + s * 16 + col)) * 128
                      + h * 16 + 4 * g) = pkd;
        }
    }
}

// ---------------------------------------------------------------------------
// Kernel 3: output projection on MFMA (split-bf16 Wo). ctx bf16 row-major.
// 512 single-wave blocks (uses all CUs): wave -> 16 rows.
// ---------------------------------------------------------------------------
__global__ __launch_bounds__(64) void outproj_kernel(
    const ushort_t* __restrict__ ctxb,
    const ushort_t* __restrict__ wo_hi, const ushort_t* __restrict__ wo_lo,
    const float* __restrict__ bo, float* __restrict__ out)
{
    const int l   = threadIdx.x;
    const int col = l & 15;
    const int g   = l >> 4;
    const int row0 = blockIdx.x * 16;

    const float bval = bo[col];
    f32x4 acc = {bval, bval, bval, bval};
    const ushort_t* ar = ctxb + (size_t)(row0 + col) * 128 + g * 8;
#pragma unroll
    for (int f = 0; f < 4; ++f) {
        const bf16x8 a = *(const bf16x8*)(ar + f * 32);
        const size_t o = ((size_t)f * 64 + l) * 8;
        const bf16x8 bh_ = *(const bf16x8*)(wo_hi + o);
        const bf16x8 bl_ = *(const bf16x8*)(wo_lo + o);
        acc = __builtin_amdgcn_mfma_f32_16x16x32_bf16(a, bh_, acc, 0, 0, 0);
        acc = __builtin_amdgcn_mfma_f32_16x16x32_bf16(a, bl_, acc, 0, 0, 0);
    }
#pragma unroll
    for (int r = 0; r < 4; ++r)
        out[(size_t)(row0 + 4 * g + r) * 16 + col] = acc[r];
}

// ---------------------------------------------------------------------------
extern "C" void kernel_launch(void* const* d_in, const int* in_sizes, int n_in,
                              void* d_out, int out_size, void* d_ws, size_t ws_size,
                              hipStream_t stream)
{
    const float* query = (const float*)d_in[0];
    const float* key_  = (const float*)d_in[1];
    const float* value = (const float*)d_in[2];
    const float* Wq = (const float*)d_in[3];
    const float* bq = (const float*)d_in[4];
    const float* Wk = (const float*)d_in[5];
    const float* bk = (const float*)d_in[6];
    const float* Wv = (const float*)d_in[7];
    const float* bv = (const float*)d_in[8];
    const float* Wo = (const float*)d_in[9];
    const float* bo = (const float*)d_in[10];
    float* out = (float*)d_out;

    ushort_t* base = (ushort_t*)d_ws;
    ushort_t* q_hi = base;
    ushort_t* q_lo = base + (1u << 20);
    ushort_t* k_hi = base + (2u << 20);
    ushort_t* k_lo = base + (3u << 20);
    ushort_t* vt   = base + (4u << 20);
    ushort_t* ctxb = base + (5u << 20);
    ushort_t* wpk_hi = base + (6u << 20);
    ushort_t* wpk_lo = wpk_hi + 32768;
    ushort_t* wo_hi  = wpk_hi + 65536;
    ushort_t* wo_lo  = wo_hi + 2048;

    wpack_kernel<<<dim3(17), dim3(256), 0, stream>>>(
        Wq, Wk, Wo, wpk_hi, wpk_lo, wo_hi, wo_lo);
    proj_kernel<<<dim3(512), dim3(256), 0, stream>>>(
        query, key_, value, bq, bk, Wv, bv, wpk_hi, wpk_lo,
        q_hi, q_lo, k_hi, k_lo, vt);
    attn_kernel<<<dim3(1024), dim3(256), 0, stream>>>(
        q_hi, q_lo, k_hi, k_lo, vt, ctxb);
    outproj_kernel<<<dim3(512), dim3(64), 0, stream>>>(
        ctxb, wo_hi, wo_lo, bo, out);
}